// Round 1
// baseline (433.092 us; speedup 1.0000x reference)
//
#include <hip/hip_runtime.h>
#include <hip/hip_bf16.h>
#include <cstdint>
#include <cstddef>

// Problem constants
#define S_LEN 2048
#define DMODEL 2048
#define NHEADS 8
#define DHEAD 128
#define INNER_DIM 1024
#define BATCH 2

typedef __bf16 bf16;
typedef __bf16 bf16x8 __attribute__((ext_vector_type(8)));
typedef __bf16 bf16x4 __attribute__((ext_vector_type(4)));
typedef float f32x4 __attribute__((ext_vector_type(4)));

__device__ __forceinline__ void gload_lds16(const void* g, void* l) {
  __builtin_amdgcn_global_load_lds(
      (const __attribute__((address_space(1))) void*)g,
      (__attribute__((address_space(3))) void*)l, 16, 0, 0);
}

__device__ __forceinline__ float sigmoidf_(float x) {
  return 1.0f / (1.0f + expf(-x));
}

// ---------------------------------------------------------------------------
// Convert fp32 inputs -> bf16 (x, Wq, Wk, Wv, Wo) in one pass.
// Flat 4-element index over concatenated arrays.
// ---------------------------------------------------------------------------
__global__ __launch_bounds__(256) void convert_kernel(
    const float* __restrict__ x, const float* __restrict__ wq,
    const float* __restrict__ wk, const float* __restrict__ wv,
    const float* __restrict__ wo, bf16* __restrict__ xb,
    bf16* __restrict__ wqb, bf16* __restrict__ wkb, bf16* __restrict__ wvb,
    bf16* __restrict__ wob) {
  size_t i4 = ((size_t)blockIdx.x * 256 + threadIdx.x) * 4;
  const float* src;
  bf16* dst;
  size_t off;
  if (i4 < 8388608UL)        { src = x;  dst = xb;  off = i4; }
  else if (i4 < 10485760UL)  { src = wq; dst = wqb; off = i4 - 8388608UL; }
  else if (i4 < 12582912UL)  { src = wk; dst = wkb; off = i4 - 10485760UL; }
  else if (i4 < 14680064UL)  { src = wv; dst = wvb; off = i4 - 12582912UL; }
  else                       { src = wo; dst = wob; off = i4 - 14680064UL; }
  float4 v = *(const float4*)(src + off);
  bf16x4 o;
  o[0] = (bf16)v.x; o[1] = (bf16)v.y; o[2] = (bf16)v.z; o[3] = (bf16)v.w;
  *(bf16x4*)(dst + off) = o;
}

// ---------------------------------------------------------------------------
// Per-head alpha: la_mean[h] = log(clip(mean_d sigmoid(alpha_log[h,d]),1e-6))
//                 la_d[h,d]  = log(sigmoid(alpha_log[h,d]))
// grid 8 x 64
// ---------------------------------------------------------------------------
__global__ __launch_bounds__(64) void alpha_kernel(
    const float* __restrict__ alpha_log, float* __restrict__ la_mean,
    float* __restrict__ la_d) {
  int h = blockIdx.x;
  int lane = threadIdx.x;
  float a1 = sigmoidf_(alpha_log[h * 128 + lane]);
  float a2 = sigmoidf_(alpha_log[h * 128 + 64 + lane]);
  la_d[h * 128 + lane] = logf(a1);
  la_d[h * 128 + 64 + lane] = logf(a2);
  float s = a1 + a2;
  for (int off = 32; off; off >>= 1) s += __shfl_down(s, off);
  if (lane == 0) la_mean[h] = logf(fmaxf(s * (1.0f / 128.0f), 1e-6f));
}

// ---------------------------------------------------------------------------
// beta[n,h] = sigmoid(x[n,:] . Wb[h,:] + bb[h]); one wave per row n.
// ---------------------------------------------------------------------------
__global__ __launch_bounds__(64) void beta_kernel(
    const float* __restrict__ x, const float* __restrict__ Wb,
    const float* __restrict__ bbias, float* __restrict__ beta) {
  int n = blockIdx.x;
  int lane = threadIdx.x;
  float acc[8];
#pragma unroll
  for (int h = 0; h < 8; h++) acc[h] = 0.0f;
  const float4* x4 = (const float4*)(x + (size_t)n * DMODEL);
  for (int d4 = lane; d4 < DMODEL / 4; d4 += 64) {
    float4 xv = x4[d4];
#pragma unroll
    for (int h = 0; h < 8; h++) {
      float4 wv = ((const float4*)(Wb + (size_t)h * DMODEL))[d4];
      acc[h] += xv.x * wv.x + xv.y * wv.y + xv.z * wv.z + xv.w * wv.w;
    }
  }
#pragma unroll
  for (int off = 32; off; off >>= 1)
#pragma unroll
    for (int h = 0; h < 8; h++) acc[h] += __shfl_down(acc[h], off);
  if (lane == 0) {
#pragma unroll
    for (int h = 0; h < 8; h++)
      beta[(size_t)n * 8 + h] = sigmoidf_(acc[h] + bbias[h]);
  }
}

// ---------------------------------------------------------------------------
// bf16 NT GEMM (m97 structure): C[M,N] = A[M,K] * B[N,K]^T, C fp32.
// 128x128 tile / 4 waves / 16x16x32 MFMA / global_load_lds width-16 staging.
// blockIdx.z selects B/C via strides (for fused QKV).
// ---------------------------------------------------------------------------
__global__ __launch_bounds__(256) void gemm_bt_kernel(
    const bf16* __restrict__ A, const bf16* __restrict__ Bm,
    float* __restrict__ C, int K, int N, size_t strideB, size_t strideC) {
  const int z = blockIdx.z;
  const bf16* Bp = Bm + (size_t)z * strideB;
  float* Cp = C + (size_t)z * strideC;
  const int tile_n = blockIdx.x * 128;
  const int tile_m = blockIdx.y * 128;
  const int tid = threadIdx.x;
  const int lane = tid & 63;
  const int wv = tid >> 6;

  __shared__ bf16 As[128 * 32];
  __shared__ bf16 Bs[128 * 32];

  f32x4 acc[4][4];
#pragma unroll
  for (int i = 0; i < 4; i++)
#pragma unroll
    for (int j = 0; j < 4; j++) acc[i][j] = (f32x4){0.f, 0.f, 0.f, 0.f};

  const int wm = (wv >> 1) * 64;
  const int wn = (wv & 1) * 64;
  const int lr = lane & 15;
  const int lk = (lane >> 4) * 8;

  // staging addresses: wave wv covers rows [wv*32, wv*32+32) of the tile
  const int ar = wv * 32 + (lane >> 2);
  const int ac = (lane & 3) * 8;
  const bf16* Ag = A + (size_t)(tile_m + ar) * K + ac;
  const bf16* Bg = Bp + (size_t)(tile_n + ar) * K + ac;
  bf16* AsW = &As[wv * 1024];
  bf16* BsW = &Bs[wv * 1024];

  for (int k0 = 0; k0 < K; k0 += 32) {
    gload_lds16(Ag + k0, AsW);
    gload_lds16(Ag + (size_t)16 * K + k0, AsW + 512);
    gload_lds16(Bg + k0, BsW);
    gload_lds16(Bg + (size_t)16 * K + k0, BsW + 512);
    __syncthreads();
    bf16x8 af[4], bfr[4];
#pragma unroll
    for (int mi = 0; mi < 4; mi++)
      af[mi] = *(const bf16x8*)&As[(wm + mi * 16 + lr) * 32 + lk];
#pragma unroll
    for (int ni = 0; ni < 4; ni++)
      bfr[ni] = *(const bf16x8*)&Bs[(wn + ni * 16 + lr) * 32 + lk];
#pragma unroll
    for (int mi = 0; mi < 4; mi++)
#pragma unroll
      for (int ni = 0; ni < 4; ni++)
        acc[mi][ni] = __builtin_amdgcn_mfma_f32_16x16x32_bf16(
            af[mi], bfr[ni], acc[mi][ni], 0, 0, 0);
    __syncthreads();
  }

  const int crow0 = tile_m + wm + (lane >> 4) * 4;
  const int ccol = tile_n + wn + (lane & 15);
#pragma unroll
  for (int mi = 0; mi < 4; mi++)
#pragma unroll
    for (int ni = 0; ni < 4; ni++)
#pragma unroll
      for (int r = 0; r < 4; r++)
        Cp[(size_t)(crow0 + mi * 16 + r) * N + ccol + ni * 16] =
            acc[mi][ni][r];
}

// ---------------------------------------------------------------------------
// RoPE in place on q and k (fp32). idx over (n, h, j) with j in [0,64).
// ---------------------------------------------------------------------------
__global__ __launch_bounds__(256) void rope_kernel(float* __restrict__ q,
                                                   float* __restrict__ k) {
  int idx = blockIdx.x * 256 + threadIdx.x;  // < 2097152
  int j = idx & 63;
  int nh = idx >> 6;  // n*8 + h
  int n = nh >> 3;
  int s = n & (S_LEN - 1);
  float inv = expf(-(float)j * (9.210340371976184f / 64.0f));  // 10000^(-j/64)
  float f = (float)s * inv;
  float sn, c;
  sincosf(f, &sn, &c);
  size_t base = (size_t)nh * 128 + j;
  float q1 = q[base], q2 = q[base + 64];
  q[base] = q1 * c - q2 * sn;
  q[base + 64] = q2 * c + q1 * sn;
  float k1 = k[base], k2 = k[base + 64];
  k[base] = k1 * c - k2 * sn;
  k[base + 64] = k2 * c + k1 * sn;
}

// ---------------------------------------------------------------------------
// Banded decay attention (window 64). One block per (s-block of 64, h, b).
// Writes bf16 attention output (input to the Wo GEMM).
// ---------------------------------------------------------------------------
__global__ __launch_bounds__(256) void attn_kernel(
    const float* __restrict__ q, const float* __restrict__ k,
    const float* __restrict__ v, const float* __restrict__ beta,
    const float* __restrict__ la_mean, bf16* __restrict__ outb) {
  const int s0 = blockIdx.x * 64;
  const int h = blockIdx.y;
  const int b = blockIdx.z;
  const int tid = threadIdx.x;

  __shared__ float qs[64][132];
  __shared__ float ks[32][132];
  __shared__ float vs[32][128];
  __shared__ float wsm[64][33];
  __shared__ float betas[32];

  const int s_l = tid >> 2;
  const int qtr = tid & 3;
  const int s_g = s0 + s_l;
  const float la = la_mean[h];
  const size_t bh_off = ((size_t)b * S_LEN) * INNER_DIM + (size_t)h * 128;

  // load q tile
  for (int e = tid * 4; e < 64 * 128; e += 1024) {
    int r = e >> 7, d = e & 127;
    *(float4*)&qs[r][d] =
        *(const float4*)&q[bh_off + (size_t)(s0 + r) * INNER_DIM + d];
  }

  float acc[32];
#pragma unroll
  for (int i = 0; i < 32; i++) acc[i] = 0.0f;

  for (int tb = s0 - 64; tb <= s0 + 32; tb += 32) {
    __syncthreads();
    // stage k/v rows t = tb..tb+31
    for (int e = tid * 4; e < 32 * 128; e += 1024) {
      int r = e >> 7, d = e & 127;
      int t = tb + r;
      float4 kv = {0.f, 0.f, 0.f, 0.f}, vv = {0.f, 0.f, 0.f, 0.f};
      if (t >= 0) {
        kv = *(const float4*)&k[bh_off + (size_t)t * INNER_DIM + d];
        vv = *(const float4*)&v[bh_off + (size_t)t * INNER_DIM + d];
      }
      *(float4*)&ks[r][d] = kv;
      *(float4*)&vs[r][d] = vv;
    }
    if (tid < 32) {
      int t = tb + tid;
      betas[tid] = (t >= 0) ? beta[((size_t)b * S_LEN + t) * 8 + h] : 0.0f;
    }
    __syncthreads();
    // phase 1: scores -> weights
#pragma unroll
    for (int jj = 0; jj < 8; jj++) {
      int tl = qtr * 8 + jj;
      int t = tb + tl;
      int td = s_g - t;
      float w = 0.0f;
      if (t >= 0 && td >= 0 && td < 64) {
        float dot = 0.0f;
#pragma unroll
        for (int d = 0; d < 128; d += 4) {
          float4 qv = *(const float4*)&qs[s_l][d];
          float4 kv = *(const float4*)&ks[tl][d];
          dot = fmaf(qv.x, kv.x,
                fmaf(qv.y, kv.y, fmaf(qv.z, kv.z, fmaf(qv.w, kv.w, dot))));
        }
        w = dot * __expf((float)td * la) * betas[tl];
      }
      wsm[s_l][tl] = w;
    }
    __syncthreads();
    // phase 2: accumulate weights * v
    for (int tl = 0; tl < 32; tl++) {
      float w = wsm[s_l][tl];
      if (w != 0.0f) {
#pragma unroll
        for (int e4 = 0; e4 < 32; e4 += 4) {
          float4 vv = *(const float4*)&vs[tl][qtr * 32 + e4];
          acc[e4 + 0] = fmaf(w, vv.x, acc[e4 + 0]);
          acc[e4 + 1] = fmaf(w, vv.y, acc[e4 + 1]);
          acc[e4 + 2] = fmaf(w, vv.z, acc[e4 + 2]);
          acc[e4 + 3] = fmaf(w, vv.w, acc[e4 + 3]);
        }
      }
    }
  }
  // write bf16 output
  size_t ob = bh_off + (size_t)s_g * INNER_DIM + qtr * 32;
#pragma unroll
  for (int e4 = 0; e4 < 32; e4 += 4) {
    bf16x4 o;
    o[0] = (bf16)acc[e4 + 0];
    o[1] = (bf16)acc[e4 + 1];
    o[2] = (bf16)acc[e4 + 2];
    o[3] = (bf16)acc[e4 + 3];
    *(bf16x4*)(outb + ob + e4) = o;
  }
}

// ---------------------------------------------------------------------------
// Final recurrent state: state[b,h,d,e] = sum_t beta*k[t,d]*v[t,e]*alpha^(S-1-t)
// Only last 512 steps survive f32 underflow. grid (B*H, 8 chunks of 64).
// Partials combined via atomicAdd into a zeroed region.
// ---------------------------------------------------------------------------
__global__ __launch_bounds__(256) void state_kernel(
    const float* __restrict__ k, const float* __restrict__ v,
    const float* __restrict__ beta, const float* __restrict__ la_d,
    float* __restrict__ state) {
  const int bh = blockIdx.x;
  const int b = bh >> 3, h = bh & 7;
  const int t0 = S_LEN - 512 + blockIdx.y * 64;
  const int tid = threadIdx.x;
  const int d = tid >> 1;
  const int eh = (tid & 1) * 64;

  __shared__ float ks[64][128];
  __shared__ float vsm[64][128];
  __shared__ float bs[64];

  const size_t bh_off = ((size_t)b * S_LEN) * INNER_DIM + (size_t)h * 128;
  for (int e = tid * 4; e < 64 * 128; e += 1024) {
    int r = e >> 7, dd = e & 127;
    *(float4*)&ks[r][dd] =
        *(const float4*)&k[bh_off + (size_t)(t0 + r) * INNER_DIM + dd];
    *(float4*)&vsm[r][dd] =
        *(const float4*)&v[bh_off + (size_t)(t0 + r) * INNER_DIM + dd];
  }
  if (tid < 64) bs[tid] = beta[((size_t)b * S_LEN + t0 + tid) * 8 + h];
  __syncthreads();

  const float lad = la_d[h * 128 + d];
  float acc[64];
#pragma unroll
  for (int e = 0; e < 64; e++) acc[e] = 0.0f;

  for (int tl = 0; tl < 64; tl++) {
    int m = (S_LEN - 1) - (t0 + tl);
    float f = __expf((float)m * lad);
    float coef = bs[tl] * ks[tl][d] * f;
    if (coef != 0.0f) {
#pragma unroll
      for (int e = 0; e < 64; e += 4) {
        float4 vv = *(const float4*)&vsm[tl][eh + e];
        acc[e + 0] = fmaf(coef, vv.x, acc[e + 0]);
        acc[e + 1] = fmaf(coef, vv.y, acc[e + 1]);
        acc[e + 2] = fmaf(coef, vv.z, acc[e + 2]);
        acc[e + 3] = fmaf(coef, vv.w, acc[e + 3]);
      }
    }
  }
  float* sp = state + (((size_t)bh * 128 + d) * 128 + eh);
  for (int e = 0; e < 64; e++) atomicAdd(&sp[e], acc[e]);
}

// ---------------------------------------------------------------------------
extern "C" void kernel_launch(void* const* d_in, const int* in_sizes, int n_in,
                              void* d_out, int out_size, void* d_ws,
                              size_t ws_size, hipStream_t stream) {
  const float* x = (const float*)d_in[0];
  const float* Wq = (const float*)d_in[1];
  const float* Wk = (const float*)d_in[2];
  const float* Wv = (const float*)d_in[3];
  const float* Wo = (const float*)d_in[4];
  const float* Wb = (const float*)d_in[5];
  const float* bb = (const float*)d_in[6];
  const float* alog = (const float*)d_in[7];
  float* out = (float*)d_out;

  char* ws = (char*)d_ws;
  bf16* xb = (bf16*)(ws);                         // 16,777,216 B
  bf16* wqb = (bf16*)(ws + 16777216UL);           // 3 x 4,194,304 B (q,k,v W)
  bf16* wob = (bf16*)(ws + 29360128UL);           // 4,194,304 B
  float* q = (float*)(ws + 33554432UL);           // 16,777,216 B
  float* kk = (float*)(ws + 50331648UL);          // 16,777,216 B
  float* vv = (float*)(ws + 67108864UL);          // 16,777,216 B
  bf16* attnb = (bf16*)(ws + 83886080UL);         // 8,388,608 B
  float* beta = (float*)(ws + 92274688UL);        // 131,072 B
  float* la_mean = (float*)(ws + 92405760UL);     // 32 B
  float* la_d = (float*)(ws + 92405792UL);        // 4,096 B

  convert_kernel<<<16384, 256, 0, stream>>>(x, Wq, Wk, Wv, Wo, xb, wqb,
                                            wqb + 2097152, wqb + 4194304, wob);
  alpha_kernel<<<8, 64, 0, stream>>>(alog, la_mean, la_d);
  beta_kernel<<<BATCH * S_LEN, 64, 0, stream>>>(x, Wb, bb, beta);
  // fused QKV GEMM: z in {0,1,2} selects Wq/Wk/Wv and q/k/v
  gemm_bt_kernel<<<dim3(INNER_DIM / 128, (BATCH * S_LEN) / 128, 3), 256, 0,
                   stream>>>(xb, wqb, q, DMODEL, INNER_DIM, 2097152UL,
                             4194304UL);
  rope_kernel<<<8192, 256, 0, stream>>>(q, kk);
  attn_kernel<<<dim3(S_LEN / 64, NHEADS, BATCH), 256, 0, stream>>>(
      q, kk, vv, beta, la_mean, attnb);
  // zero the state region, then accumulate partial chunks
  hipMemsetAsync(out + 8388608, 0, 262144 * sizeof(float), stream);
  state_kernel<<<dim3(BATCH * NHEADS, 8), 256, 0, stream>>>(kk, vv, beta, la_d,
                                                            out + 8388608);
  // output projection into d_out[0 : B*S*DM)
  gemm_bt_kernel<<<dim3(DMODEL / 128, (BATCH * S_LEN) / 128, 1), 256, 0,
                   stream>>>(attnb, wob, out, INNER_DIM, DMODEL, 0, 0);
}

// Round 2
// 333.216 us; speedup vs baseline: 1.2997x; 1.2997x over previous
//
#include <hip/hip_runtime.h>
#include <hip/hip_bf16.h>
#include <cstdint>
#include <cstddef>

// Problem constants
#define S_LEN 2048
#define DMODEL 2048
#define NHEADS 8
#define DHEAD 128
#define INNER_DIM 1024
#define BATCH 2

typedef __bf16 bf16;
typedef __bf16 bf16x8 __attribute__((ext_vector_type(8)));
typedef __bf16 bf16x4 __attribute__((ext_vector_type(4)));
typedef float f32x4 __attribute__((ext_vector_type(4)));

__device__ __forceinline__ void gload_lds16(const void* g, void* l) {
  __builtin_amdgcn_global_load_lds(
      (const __attribute__((address_space(1))) void*)g,
      (__attribute__((address_space(3))) void*)l, 16, 0, 0);
}

__device__ __forceinline__ float sigmoidf_(float x) {
  return 1.0f / (1.0f + expf(-x));
}

// ---------------------------------------------------------------------------
// Convert fp32 inputs -> bf16 (x, Wq, Wk, Wv, Wo) in one pass.
// ---------------------------------------------------------------------------
__global__ __launch_bounds__(256) void convert_kernel(
    const float* __restrict__ x, const float* __restrict__ wq,
    const float* __restrict__ wk, const float* __restrict__ wv,
    const float* __restrict__ wo, bf16* __restrict__ xb,
    bf16* __restrict__ wqb, bf16* __restrict__ wkb, bf16* __restrict__ wvb,
    bf16* __restrict__ wob) {
  size_t i4 = ((size_t)blockIdx.x * 256 + threadIdx.x) * 4;
  const float* src;
  bf16* dst;
  size_t off;
  if (i4 < 8388608UL)        { src = x;  dst = xb;  off = i4; }
  else if (i4 < 10485760UL)  { src = wq; dst = wqb; off = i4 - 8388608UL; }
  else if (i4 < 12582912UL)  { src = wk; dst = wkb; off = i4 - 10485760UL; }
  else if (i4 < 14680064UL)  { src = wv; dst = wvb; off = i4 - 12582912UL; }
  else                       { src = wo; dst = wob; off = i4 - 14680064UL; }
  float4 v = *(const float4*)(src + off);
  bf16x4 o;
  o[0] = (bf16)v.x; o[1] = (bf16)v.y; o[2] = (bf16)v.z; o[3] = (bf16)v.w;
  *(bf16x4*)(dst + off) = o;
}

// ---------------------------------------------------------------------------
// Per-head alpha: la_mean[h] = log(clip(mean_d sigmoid(alpha_log[h,d]),1e-6))
//                 la_d[h,d]  = log(sigmoid(alpha_log[h,d]))
// ---------------------------------------------------------------------------
__global__ __launch_bounds__(64) void alpha_kernel(
    const float* __restrict__ alpha_log, float* __restrict__ la_mean,
    float* __restrict__ la_d) {
  int h = blockIdx.x;
  int lane = threadIdx.x;
  float a1 = sigmoidf_(alpha_log[h * 128 + lane]);
  float a2 = sigmoidf_(alpha_log[h * 128 + 64 + lane]);
  la_d[h * 128 + lane] = logf(a1);
  la_d[h * 128 + 64 + lane] = logf(a2);
  float s = a1 + a2;
  for (int off = 32; off; off >>= 1) s += __shfl_down(s, off);
  if (lane == 0) la_mean[h] = logf(fmaxf(s * (1.0f / 128.0f), 1e-6f));
}

// ---------------------------------------------------------------------------
// beta[n,h] = sigmoid(x[n,:] . Wb[h,:] + bb[h]); one wave per row n.
// ---------------------------------------------------------------------------
__global__ __launch_bounds__(64) void beta_kernel(
    const float* __restrict__ x, const float* __restrict__ Wb,
    const float* __restrict__ bbias, float* __restrict__ beta) {
  int n = blockIdx.x;
  int lane = threadIdx.x;
  float acc[8];
#pragma unroll
  for (int h = 0; h < 8; h++) acc[h] = 0.0f;
  const float4* x4 = (const float4*)(x + (size_t)n * DMODEL);
  for (int d4 = lane; d4 < DMODEL / 4; d4 += 64) {
    float4 xv = x4[d4];
#pragma unroll
    for (int h = 0; h < 8; h++) {
      float4 wv = ((const float4*)(Wb + (size_t)h * DMODEL))[d4];
      acc[h] += xv.x * wv.x + xv.y * wv.y + xv.z * wv.z + xv.w * wv.w;
    }
  }
#pragma unroll
  for (int off = 32; off; off >>= 1)
#pragma unroll
    for (int h = 0; h < 8; h++) acc[h] += __shfl_down(acc[h], off);
  if (lane == 0) {
#pragma unroll
    for (int h = 0; h < 8; h++)
      beta[(size_t)n * 8 + h] = sigmoidf_(acc[h] + bbias[h]);
  }
}

// ---------------------------------------------------------------------------
// bf16 NT GEMM (m97 structure): C[M,N] = A[M,K] * B[N,K]^T, C fp32.
// ---------------------------------------------------------------------------
__global__ __launch_bounds__(256) void gemm_bt_kernel(
    const bf16* __restrict__ A, const bf16* __restrict__ Bm,
    float* __restrict__ C, int K, int N, size_t strideB, size_t strideC) {
  const int z = blockIdx.z;
  const bf16* Bp = Bm + (size_t)z * strideB;
  float* Cp = C + (size_t)z * strideC;
  const int tile_n = blockIdx.x * 128;
  const int tile_m = blockIdx.y * 128;
  const int tid = threadIdx.x;
  const int lane = tid & 63;
  const int wv = tid >> 6;

  __shared__ bf16 As[128 * 32];
  __shared__ bf16 Bs[128 * 32];

  f32x4 acc[4][4];
#pragma unroll
  for (int i = 0; i < 4; i++)
#pragma unroll
    for (int j = 0; j < 4; j++) acc[i][j] = (f32x4){0.f, 0.f, 0.f, 0.f};

  const int wm = (wv >> 1) * 64;
  const int wn = (wv & 1) * 64;
  const int lr = lane & 15;
  const int lk = (lane >> 4) * 8;

  const int ar = wv * 32 + (lane >> 2);
  const int ac = (lane & 3) * 8;
  const bf16* Ag = A + (size_t)(tile_m + ar) * K + ac;
  const bf16* Bg = Bp + (size_t)(tile_n + ar) * K + ac;
  bf16* AsW = &As[wv * 1024];
  bf16* BsW = &Bs[wv * 1024];

  for (int k0 = 0; k0 < K; k0 += 32) {
    gload_lds16(Ag + k0, AsW);
    gload_lds16(Ag + (size_t)16 * K + k0, AsW + 512);
    gload_lds16(Bg + k0, BsW);
    gload_lds16(Bg + (size_t)16 * K + k0, BsW + 512);
    __syncthreads();
    bf16x8 af[4], bfr[4];
#pragma unroll
    for (int mi = 0; mi < 4; mi++)
      af[mi] = *(const bf16x8*)&As[(wm + mi * 16 + lr) * 32 + lk];
#pragma unroll
    for (int ni = 0; ni < 4; ni++)
      bfr[ni] = *(const bf16x8*)&Bs[(wn + ni * 16 + lr) * 32 + lk];
#pragma unroll
    for (int mi = 0; mi < 4; mi++)
#pragma unroll
      for (int ni = 0; ni < 4; ni++)
        acc[mi][ni] = __builtin_amdgcn_mfma_f32_16x16x32_bf16(
            af[mi], bfr[ni], acc[mi][ni], 0, 0, 0);
    __syncthreads();
  }

  const int crow0 = tile_m + wm + (lane >> 4) * 4;
  const int ccol = tile_n + wn + (lane & 15);
#pragma unroll
  for (int mi = 0; mi < 4; mi++)
#pragma unroll
    for (int ni = 0; ni < 4; ni++)
#pragma unroll
      for (int r = 0; r < 4; r++)
        Cp[(size_t)(crow0 + mi * 16 + r) * N + ccol + ni * 16] =
            acc[mi][ni][r];
}

// ---------------------------------------------------------------------------
// RoPE in place on q and k (fp32).
// ---------------------------------------------------------------------------
__global__ __launch_bounds__(256) void rope_kernel(float* __restrict__ q,
                                                   float* __restrict__ k) {
  int idx = blockIdx.x * 256 + threadIdx.x;  // < 2097152
  int j = idx & 63;
  int nh = idx >> 6;  // n*8 + h
  int n = nh >> 3;
  int s = n & (S_LEN - 1);
  float inv = expf(-(float)j * (9.210340371976184f / 64.0f));  // 10000^(-j/64)
  float f = (float)s * inv;
  float sn, c;
  sincosf(f, &sn, &c);
  size_t base = (size_t)nh * 128 + j;
  float q1 = q[base], q2 = q[base + 64];
  q[base] = q1 * c - q2 * sn;
  q[base + 64] = q2 * c + q1 * sn;
  float k1 = k[base], k2 = k[base + 64];
  k[base] = k1 * c - k2 * sn;
  k[base + 64] = k2 * c + k1 * sn;
}

// ---------------------------------------------------------------------------
// Banded decay attention (window 64). One block per (s-block of 64, h, b).
// ---------------------------------------------------------------------------
__global__ __launch_bounds__(256) void attn_kernel(
    const float* __restrict__ q, const float* __restrict__ k,
    const float* __restrict__ v, const float* __restrict__ beta,
    const float* __restrict__ la_mean, bf16* __restrict__ outb) {
  const int s0 = blockIdx.x * 64;
  const int h = blockIdx.y;
  const int b = blockIdx.z;
  const int tid = threadIdx.x;

  __shared__ float qs[64][132];
  __shared__ float ks[32][132];
  __shared__ float vs[32][128];
  __shared__ float wsm[64][33];
  __shared__ float betas[32];

  const int s_l = tid >> 2;
  const int qtr = tid & 3;
  const int s_g = s0 + s_l;
  const float la = la_mean[h];
  const size_t bh_off = ((size_t)b * S_LEN) * INNER_DIM + (size_t)h * 128;

  for (int e = tid * 4; e < 64 * 128; e += 1024) {
    int r = e >> 7, d = e & 127;
    *(float4*)&qs[r][d] =
        *(const float4*)&q[bh_off + (size_t)(s0 + r) * INNER_DIM + d];
  }

  float acc[32];
#pragma unroll
  for (int i = 0; i < 32; i++) acc[i] = 0.0f;

  for (int tb = s0 - 64; tb <= s0 + 32; tb += 32) {
    __syncthreads();
    for (int e = tid * 4; e < 32 * 128; e += 1024) {
      int r = e >> 7, d = e & 127;
      int t = tb + r;
      float4 kv = {0.f, 0.f, 0.f, 0.f}, vv = {0.f, 0.f, 0.f, 0.f};
      if (t >= 0) {
        kv = *(const float4*)&k[bh_off + (size_t)t * INNER_DIM + d];
        vv = *(const float4*)&v[bh_off + (size_t)t * INNER_DIM + d];
      }
      *(float4*)&ks[r][d] = kv;
      *(float4*)&vs[r][d] = vv;
    }
    if (tid < 32) {
      int t = tb + tid;
      betas[tid] = (t >= 0) ? beta[((size_t)b * S_LEN + t) * 8 + h] : 0.0f;
    }
    __syncthreads();
#pragma unroll
    for (int jj = 0; jj < 8; jj++) {
      int tl = qtr * 8 + jj;
      int t = tb + tl;
      int td = s_g - t;
      float w = 0.0f;
      if (t >= 0 && td >= 0 && td < 64) {
        float dot = 0.0f;
#pragma unroll
        for (int d = 0; d < 128; d += 4) {
          float4 qv = *(const float4*)&qs[s_l][d];
          float4 kv = *(const float4*)&ks[tl][d];
          dot = fmaf(qv.x, kv.x,
                fmaf(qv.y, kv.y, fmaf(qv.z, kv.z, fmaf(qv.w, kv.w, dot))));
        }
        w = dot * __expf((float)td * la) * betas[tl];
      }
      wsm[s_l][tl] = w;
    }
    __syncthreads();
    for (int tl = 0; tl < 32; tl++) {
      float w = wsm[s_l][tl];
      if (w != 0.0f) {
#pragma unroll
        for (int e4 = 0; e4 < 32; e4 += 4) {
          float4 vv = *(const float4*)&vs[tl][qtr * 32 + e4];
          acc[e4 + 0] = fmaf(w, vv.x, acc[e4 + 0]);
          acc[e4 + 1] = fmaf(w, vv.y, acc[e4 + 1]);
          acc[e4 + 2] = fmaf(w, vv.z, acc[e4 + 2]);
          acc[e4 + 3] = fmaf(w, vv.w, acc[e4 + 3]);
        }
      }
    }
  }
  size_t ob = bh_off + (size_t)s_g * INNER_DIM + qtr * 32;
#pragma unroll
  for (int e4 = 0; e4 < 32; e4 += 4) {
    bf16x4 o;
    o[0] = (bf16)acc[e4 + 0];
    o[1] = (bf16)acc[e4 + 1];
    o[2] = (bf16)acc[e4 + 2];
    o[3] = (bf16)acc[e4 + 3];
    *(bf16x4*)(outb + ob + e4) = o;
  }
}

// ---------------------------------------------------------------------------
// Stage 1: partial state per 32-step chunk. NO atomics — each block writes
// its own 64 KB partial with coalesced float4 stores.
// grid (16 bh, 16 chunks) = 256 blocks.
// ---------------------------------------------------------------------------
__global__ __launch_bounds__(256) void state_partial_kernel(
    const float* __restrict__ k, const float* __restrict__ v,
    const float* __restrict__ beta, const float* __restrict__ la_d,
    float* __restrict__ part) {
  const int bh = blockIdx.x;
  const int chunk = blockIdx.y;
  const int b = bh >> 3, h = bh & 7;
  const int t0 = S_LEN - 512 + chunk * 32;
  const int tid = threadIdx.x;
  const int d = tid >> 1;
  const int eh = (tid & 1) * 64;

  __shared__ float ks[32][128];
  __shared__ float vsm[32][128];
  __shared__ float bs[32];

  const size_t bh_off = ((size_t)b * S_LEN) * INNER_DIM + (size_t)h * 128;
  for (int e = tid * 4; e < 32 * 128; e += 1024) {
    int r = e >> 7, dd = e & 127;
    *(float4*)&ks[r][dd] =
        *(const float4*)&k[bh_off + (size_t)(t0 + r) * INNER_DIM + dd];
    *(float4*)&vsm[r][dd] =
        *(const float4*)&v[bh_off + (size_t)(t0 + r) * INNER_DIM + dd];
  }
  if (tid < 32) bs[tid] = beta[((size_t)b * S_LEN + t0 + tid) * 8 + h];
  __syncthreads();

  const float lad = la_d[h * 128 + d];
  float acc[64];
#pragma unroll
  for (int e = 0; e < 64; e++) acc[e] = 0.0f;

  for (int tl = 0; tl < 32; tl++) {
    int m = (S_LEN - 1) - (t0 + tl);
    float f = __expf((float)m * lad);
    float coef = bs[tl] * ks[tl][d] * f;
    if (coef != 0.0f) {
#pragma unroll
      for (int e = 0; e < 64; e += 4) {
        float4 vv = *(const float4*)&vsm[tl][eh + e];
        acc[e + 0] = fmaf(coef, vv.x, acc[e + 0]);
        acc[e + 1] = fmaf(coef, vv.y, acc[e + 1]);
        acc[e + 2] = fmaf(coef, vv.z, acc[e + 2]);
        acc[e + 3] = fmaf(coef, vv.w, acc[e + 3]);
      }
    }
  }
  float* pp = part + (((size_t)chunk * 16 + bh) * 16384 + (size_t)d * 128 + eh);
#pragma unroll
  for (int e = 0; e < 64; e += 4) {
    float4 o = {acc[e + 0], acc[e + 1], acc[e + 2], acc[e + 3]};
    *(float4*)&pp[e] = o;
  }
}

// ---------------------------------------------------------------------------
// Stage 2: sum the 16 chunk partials into the final state (overwrites — no
// memset needed). 65536 float4 elements.
// ---------------------------------------------------------------------------
__global__ __launch_bounds__(256) void state_reduce_kernel(
    const float* __restrict__ part, float* __restrict__ state) {
  size_t off = ((size_t)blockIdx.x * 256 + threadIdx.x) * 4;
  float4 s = {0.f, 0.f, 0.f, 0.f};
#pragma unroll
  for (int c = 0; c < 16; c++) {
    float4 p = *(const float4*)&part[(size_t)c * 262144 + off];
    s.x += p.x; s.y += p.y; s.z += p.z; s.w += p.w;
  }
  *(float4*)&state[off] = s;
}

// ---------------------------------------------------------------------------
extern "C" void kernel_launch(void* const* d_in, const int* in_sizes, int n_in,
                              void* d_out, int out_size, void* d_ws,
                              size_t ws_size, hipStream_t stream) {
  const float* x = (const float*)d_in[0];
  const float* Wq = (const float*)d_in[1];
  const float* Wk = (const float*)d_in[2];
  const float* Wv = (const float*)d_in[3];
  const float* Wo = (const float*)d_in[4];
  const float* Wb = (const float*)d_in[5];
  const float* bb = (const float*)d_in[6];
  const float* alog = (const float*)d_in[7];
  float* out = (float*)d_out;

  char* ws = (char*)d_ws;
  bf16* xb = (bf16*)(ws);                         // 16,777,216 B
  float* part = (float*)(ws);                     // reuses xb region (16 MB)
  bf16* wqb = (bf16*)(ws + 16777216UL);           // 3 x 4,194,304 B (q,k,v W)
  bf16* wob = (bf16*)(ws + 29360128UL);           // 4,194,304 B
  float* q = (float*)(ws + 33554432UL);           // 16,777,216 B
  float* kk = (float*)(ws + 50331648UL);          // 16,777,216 B
  float* vv = (float*)(ws + 67108864UL);          // 16,777,216 B
  bf16* attnb = (bf16*)(ws + 83886080UL);         // 8,388,608 B
  float* beta = (float*)(ws + 92274688UL);        // 131,072 B
  float* la_mean = (float*)(ws + 92405760UL);     // 32 B
  float* la_d = (float*)(ws + 92405792UL);        // 4,096 B

  convert_kernel<<<16384, 256, 0, stream>>>(x, Wq, Wk, Wv, Wo, xb, wqb,
                                            wqb + 2097152, wqb + 4194304, wob);
  alpha_kernel<<<8, 64, 0, stream>>>(alog, la_mean, la_d);
  beta_kernel<<<BATCH * S_LEN, 64, 0, stream>>>(x, Wb, bb, beta);
  gemm_bt_kernel<<<dim3(INNER_DIM / 128, (BATCH * S_LEN) / 128, 3), 256, 0,
                   stream>>>(xb, wqb, q, DMODEL, INNER_DIM, 2097152UL,
                             4194304UL);
  rope_kernel<<<8192, 256, 0, stream>>>(q, kk);
  attn_kernel<<<dim3(S_LEN / 64, NHEADS, BATCH), 256, 0, stream>>>(
      q, kk, vv, beta, la_mean, attnb);
  // state: partials (reusing xb region — xb is dead after the QKV GEMM),
  // then reduce directly into d_out (no memset, no atomics).
  state_partial_kernel<<<dim3(16, 16), 256, 0, stream>>>(kk, vv, beta, la_d,
                                                         part);
  state_reduce_kernel<<<256, 256, 0, stream>>>(part, out + 8388608);
  gemm_bt_kernel<<<dim3(DMODEL / 128, (BATCH * S_LEN) / 128, 1), 256, 0,
                   stream>>>(attnb, wob, out, INNER_DIM, DMODEL, 0, 0);
}

// Round 3
// 321.697 us; speedup vs baseline: 1.3463x; 1.0358x over previous
//
#include <hip/hip_runtime.h>
#include <hip/hip_bf16.h>
#include <cstdint>
#include <cstddef>

// Problem constants
#define S_LEN 2048
#define DMODEL 2048
#define NHEADS 8
#define DHEAD 128
#define INNER_DIM 1024
#define BATCH 2

typedef __bf16 bf16;
typedef __bf16 bf16x8 __attribute__((ext_vector_type(8)));
typedef __bf16 bf16x4 __attribute__((ext_vector_type(4)));
typedef float f32x4 __attribute__((ext_vector_type(4)));

__device__ __forceinline__ void gload_lds16(const void* g, void* l) {
  __builtin_amdgcn_global_load_lds(
      (const __attribute__((address_space(1))) void*)g,
      (__attribute__((address_space(3))) void*)l, 16, 0, 0);
}

__device__ __forceinline__ float sigmoidf_(float x) {
  return 1.0f / (1.0f + expf(-x));
}

// ---------------------------------------------------------------------------
// Convert fp32 weights -> bf16 (Wq, Wk, Wv laid out contiguously, then Wo).
// 8,388,608 elems / 4 per thread / 256 per block = 8192 blocks.
// ---------------------------------------------------------------------------
__global__ __launch_bounds__(256) void convert_w_kernel(
    const float* __restrict__ wq, const float* __restrict__ wk,
    const float* __restrict__ wv, const float* __restrict__ wo,
    bf16* __restrict__ wqkvb, bf16* __restrict__ wob) {
  size_t i4 = ((size_t)blockIdx.x * 256 + threadIdx.x) * 4;
  const float* src;
  bf16* dst;
  size_t off;
  if (i4 < 2097152UL)       { src = wq; dst = wqkvb;           off = i4; }
  else if (i4 < 4194304UL)  { src = wk; dst = wqkvb + 2097152; off = i4 - 2097152UL; }
  else if (i4 < 6291456UL)  { src = wv; dst = wqkvb + 4194304; off = i4 - 4194304UL; }
  else                      { src = wo; dst = wob;             off = i4 - 6291456UL; }
  float4 v = *(const float4*)(src + off);
  bf16x4 o;
  o[0] = (bf16)v.x; o[1] = (bf16)v.y; o[2] = (bf16)v.z; o[3] = (bf16)v.w;
  *(bf16x4*)(dst + off) = o;
}

// ---------------------------------------------------------------------------
// Per-head alpha: la_mean[h] = log(clip(mean_d sigmoid(alpha_log[h,d]),1e-6))
//                 la_d[h,d]  = log(sigmoid(alpha_log[h,d]))
// ---------------------------------------------------------------------------
__global__ __launch_bounds__(64) void alpha_kernel(
    const float* __restrict__ alpha_log, float* __restrict__ la_mean,
    float* __restrict__ la_d) {
  int h = blockIdx.x;
  int lane = threadIdx.x;
  float a1 = sigmoidf_(alpha_log[h * 128 + lane]);
  float a2 = sigmoidf_(alpha_log[h * 128 + 64 + lane]);
  la_d[h * 128 + lane] = logf(a1);
  la_d[h * 128 + 64 + lane] = logf(a2);
  float s = a1 + a2;
  for (int off = 32; off; off >>= 1) s += __shfl_down(s, off);
  if (lane == 0) la_mean[h] = logf(fmaxf(s * (1.0f / 128.0f), 1e-6f));
}

// ---------------------------------------------------------------------------
// beta[n,h] = sigmoid(x[n,:].Wb[h,:] + bb[h]); also emits xb = bf16(x).
// One wave per row n (reads x once, serves both purposes).
// ---------------------------------------------------------------------------
__global__ __launch_bounds__(64) void beta_xb_kernel(
    const float* __restrict__ x, const float* __restrict__ Wb,
    const float* __restrict__ bbias, float* __restrict__ beta,
    bf16* __restrict__ xb) {
  int n = blockIdx.x;
  int lane = threadIdx.x;
  float acc[8];
#pragma unroll
  for (int h = 0; h < 8; h++) acc[h] = 0.0f;
  const float4* x4 = (const float4*)(x + (size_t)n * DMODEL);
  bf16* xbr = xb + (size_t)n * DMODEL;
  for (int d4 = lane; d4 < DMODEL / 4; d4 += 64) {
    float4 xv = x4[d4];
    bf16x4 o;
    o[0] = (bf16)xv.x; o[1] = (bf16)xv.y; o[2] = (bf16)xv.z; o[3] = (bf16)xv.w;
    *(bf16x4*)(xbr + d4 * 4) = o;
#pragma unroll
    for (int h = 0; h < 8; h++) {
      float4 wv = ((const float4*)(Wb + (size_t)h * DMODEL))[d4];
      acc[h] += xv.x * wv.x + xv.y * wv.y + xv.z * wv.z + xv.w * wv.w;
    }
  }
#pragma unroll
  for (int off = 32; off; off >>= 1)
#pragma unroll
    for (int h = 0; h < 8; h++) acc[h] += __shfl_down(acc[h], off);
  if (lane == 0) {
#pragma unroll
    for (int h = 0; h < 8; h++)
      beta[(size_t)n * 8 + h] = sigmoidf_(acc[h] + bbias[h]);
  }
}

// ---------------------------------------------------------------------------
// bf16 NT GEMM, XOR-swizzled LDS to kill bank conflicts.
// LDS row = 32 bf16 (64 B) = 4 x 16B blocks. Physical block p holds global
// k-block p ^ ((row>>1)&3). Staging swizzles the GLOBAL source per lane
// (global_load_lds dest is pinned to base + lane*16); reads use q ^ swz.
// obf: 1 -> store bf16, 0 -> store f32.
// ---------------------------------------------------------------------------
__global__ __launch_bounds__(256) void gemm_bt_kernel(
    const bf16* __restrict__ A, const bf16* __restrict__ Bm, void* Cv, int K,
    int N, size_t strideB, size_t strideC, int obf) {
  const int z = blockIdx.z;
  const bf16* Bp = Bm + (size_t)z * strideB;
  const int tile_n = blockIdx.x * 128;
  const int tile_m = blockIdx.y * 128;
  const int tid = threadIdx.x;
  const int lane = tid & 63;
  const int wv = tid >> 6;

  __shared__ bf16 As[128 * 32];
  __shared__ bf16 Bs[128 * 32];

  f32x4 acc[4][4];
#pragma unroll
  for (int i = 0; i < 4; i++)
#pragma unroll
    for (int j = 0; j < 4; j++) acc[i][j] = (f32x4){0.f, 0.f, 0.f, 0.f};

  const int wm = (wv >> 1) * 64;
  const int wn = (wv & 1) * 64;
  const int lr = lane & 15;
  const int kq = lane >> 4;
  // read-side swizzle (invariant across mi/ni: +16 rows preserves (row>>1)&3)
  const int koffA = ((kq ^ ((wm + lr) >> 1)) & 3) * 8 + ((kq ^ ((wm + lr) >> 1)) & ~3) * 0;
  const int swzA = ((wm + lr) >> 1) & 3;
  const int swzB = ((wn + lr) >> 1) & 3;
  const int kA = (kq ^ swzA) * 8;
  const int kB = (kq ^ swzB) * 8;

  // staging: lane covers row ar, physical block p=lane&3; load global block
  // g = p ^ ((ar>>1)&3)  (same swz for ar+16).
  const int ar = wv * 32 + (lane >> 2);
  const int g = ((lane & 3) ^ ((ar >> 1) & 3)) * 8;
  const bf16* Ag = A + (size_t)(tile_m + ar) * K + g;
  const bf16* Bg = Bp + (size_t)(tile_n + ar) * K + g;
  bf16* AsW = &As[wv * 1024];
  bf16* BsW = &Bs[wv * 1024];

  for (int k0 = 0; k0 < K; k0 += 32) {
    gload_lds16(Ag + k0, AsW);
    gload_lds16(Ag + (size_t)16 * K + k0, AsW + 512);
    gload_lds16(Bg + k0, BsW);
    gload_lds16(Bg + (size_t)16 * K + k0, BsW + 512);
    __syncthreads();
    bf16x8 af[4], bfr[4];
#pragma unroll
    for (int mi = 0; mi < 4; mi++)
      af[mi] = *(const bf16x8*)&As[(wm + mi * 16 + lr) * 32 + kA];
#pragma unroll
    for (int ni = 0; ni < 4; ni++)
      bfr[ni] = *(const bf16x8*)&Bs[(wn + ni * 16 + lr) * 32 + kB];
#pragma unroll
    for (int mi = 0; mi < 4; mi++)
#pragma unroll
      for (int ni = 0; ni < 4; ni++)
        acc[mi][ni] = __builtin_amdgcn_mfma_f32_16x16x32_bf16(
            af[mi], bfr[ni], acc[mi][ni], 0, 0, 0);
    __syncthreads();
  }

  const int crow0 = tile_m + wm + (lane >> 4) * 4;
  const int ccol = tile_n + wn + (lane & 15);
  if (obf) {
    bf16* Cb = (bf16*)Cv + (size_t)z * strideC;
#pragma unroll
    for (int mi = 0; mi < 4; mi++)
#pragma unroll
      for (int ni = 0; ni < 4; ni++)
#pragma unroll
        for (int r = 0; r < 4; r++)
          Cb[(size_t)(crow0 + mi * 16 + r) * N + ccol + ni * 16] =
              (bf16)acc[mi][ni][r];
  } else {
    float* Cf = (float*)Cv + (size_t)z * strideC;
#pragma unroll
    for (int mi = 0; mi < 4; mi++)
#pragma unroll
      for (int ni = 0; ni < 4; ni++)
#pragma unroll
        for (int r = 0; r < 4; r++)
          Cf[(size_t)(crow0 + mi * 16 + r) * N + ccol + ni * 16] =
              acc[mi][ni][r];
  }
}

// ---------------------------------------------------------------------------
// RoPE in place on bf16 q and k. Thread handles 4 (j, j+64) pairs.
// ---------------------------------------------------------------------------
__global__ __launch_bounds__(256) void rope_kernel(bf16* __restrict__ q,
                                                   bf16* __restrict__ k) {
  int idx = blockIdx.x * 256 + threadIdx.x;  // < 524288
  int j0 = (idx & 15) * 4;
  int nh = idx >> 4;  // n*8 + h, n < 4096
  int s = (nh >> 3) & (S_LEN - 1);
  size_t base = (size_t)nh * 128 + j0;
  bf16x4 qa = *(bf16x4*)&q[base], qb = *(bf16x4*)&q[base + 64];
  bf16x4 ka = *(bf16x4*)&k[base], kb = *(bf16x4*)&k[base + 64];
#pragma unroll
  for (int jj = 0; jj < 4; jj++) {
    float inv = expf(-(float)(j0 + jj) * (9.210340371976184f / 64.0f));
    float f = (float)s * inv;
    float sn, c;
    sincosf(f, &sn, &c);
    float q1 = (float)qa[jj], q2 = (float)qb[jj];
    qa[jj] = (bf16)(q1 * c - q2 * sn);
    qb[jj] = (bf16)(q2 * c + q1 * sn);
    float k1 = (float)ka[jj], k2 = (float)kb[jj];
    ka[jj] = (bf16)(k1 * c - k2 * sn);
    kb[jj] = (bf16)(k2 * c + k1 * sn);
  }
  *(bf16x4*)&q[base] = qa;
  *(bf16x4*)&q[base + 64] = qb;
  *(bf16x4*)&k[base] = ka;
  *(bf16x4*)&k[base + 64] = kb;
}

// ---------------------------------------------------------------------------
// Banded decay attention (window 64), bf16 inputs staged to f32 LDS.
// One block per (s-block of 64, h, b).
// ---------------------------------------------------------------------------
__global__ __launch_bounds__(256) void attn_kernel(
    const bf16* __restrict__ q, const bf16* __restrict__ k,
    const bf16* __restrict__ v, const float* __restrict__ beta,
    const float* __restrict__ la_mean, bf16* __restrict__ outb) {
  const int s0 = blockIdx.x * 64;
  const int h = blockIdx.y;
  const int b = blockIdx.z;
  const int tid = threadIdx.x;

  __shared__ float qs[64][132];
  __shared__ float ks[32][132];
  __shared__ float vs[32][128];
  __shared__ float wsm[64][33];
  __shared__ float betas[32];

  const int s_l = tid >> 2;
  const int qtr = tid & 3;
  const int s_g = s0 + s_l;
  const float la = la_mean[h];
  const size_t bh_off = ((size_t)b * S_LEN) * INNER_DIM + (size_t)h * 128;

  // load q tile (64 rows x 16 groups of 8 bf16)
  for (int u = tid; u < 64 * 16; u += 256) {
    int r = u >> 4, c8 = (u & 15) * 8;
    bf16x8 t = *(const bf16x8*)&q[bh_off + (size_t)(s0 + r) * INNER_DIM + c8];
#pragma unroll
    for (int j = 0; j < 8; j++) qs[r][c8 + j] = (float)t[j];
  }

  float acc[32];
#pragma unroll
  for (int i = 0; i < 32; i++) acc[i] = 0.0f;

  for (int tb = s0 - 64; tb <= s0 + 32; tb += 32) {
    __syncthreads();
    for (int u = tid; u < 32 * 16; u += 256) {
      int r = u >> 4, c8 = (u & 15) * 8;
      int t = tb + r;
      if (t >= 0) {
        bf16x8 kv = *(const bf16x8*)&k[bh_off + (size_t)t * INNER_DIM + c8];
        bf16x8 vv = *(const bf16x8*)&v[bh_off + (size_t)t * INNER_DIM + c8];
#pragma unroll
        for (int j = 0; j < 8; j++) {
          ks[r][c8 + j] = (float)kv[j];
          vs[r][c8 + j] = (float)vv[j];
        }
      } else {
#pragma unroll
        for (int j = 0; j < 8; j++) {
          ks[r][c8 + j] = 0.0f;
          vs[r][c8 + j] = 0.0f;
        }
      }
    }
    if (tid < 32) {
      int t = tb + tid;
      betas[tid] = (t >= 0) ? beta[((size_t)b * S_LEN + t) * 8 + h] : 0.0f;
    }
    __syncthreads();
#pragma unroll
    for (int jj = 0; jj < 8; jj++) {
      int tl = qtr * 8 + jj;
      int t = tb + tl;
      int td = s_g - t;
      float w = 0.0f;
      if (t >= 0 && td >= 0 && td < 64) {
        float dot = 0.0f;
#pragma unroll
        for (int d = 0; d < 128; d += 4) {
          float4 qv = *(const float4*)&qs[s_l][d];
          float4 kv = *(const float4*)&ks[tl][d];
          dot = fmaf(qv.x, kv.x,
                fmaf(qv.y, kv.y, fmaf(qv.z, kv.z, fmaf(qv.w, kv.w, dot))));
        }
        w = dot * __expf((float)td * la) * betas[tl];
      }
      wsm[s_l][tl] = w;
    }
    __syncthreads();
    for (int tl = 0; tl < 32; tl++) {
      float w = wsm[s_l][tl];
      if (w != 0.0f) {
#pragma unroll
        for (int e4 = 0; e4 < 32; e4 += 4) {
          float4 vv = *(const float4*)&vs[tl][qtr * 32 + e4];
          acc[e4 + 0] = fmaf(w, vv.x, acc[e4 + 0]);
          acc[e4 + 1] = fmaf(w, vv.y, acc[e4 + 1]);
          acc[e4 + 2] = fmaf(w, vv.z, acc[e4 + 2]);
          acc[e4 + 3] = fmaf(w, vv.w, acc[e4 + 3]);
        }
      }
    }
  }
  size_t ob = bh_off + (size_t)s_g * INNER_DIM + qtr * 32;
#pragma unroll
  for (int e4 = 0; e4 < 32; e4 += 4) {
    bf16x4 o;
    o[0] = (bf16)acc[e4 + 0];
    o[1] = (bf16)acc[e4 + 1];
    o[2] = (bf16)acc[e4 + 2];
    o[3] = (bf16)acc[e4 + 3];
    *(bf16x4*)(outb + ob + e4) = o;
  }
}

// ---------------------------------------------------------------------------
// Stage 1: partial state per 32-step chunk (bf16 k/v inputs), no atomics.
// ---------------------------------------------------------------------------
__global__ __launch_bounds__(256) void state_partial_kernel(
    const bf16* __restrict__ k, const bf16* __restrict__ v,
    const float* __restrict__ beta, const float* __restrict__ la_d,
    float* __restrict__ part) {
  const int bh = blockIdx.x;
  const int chunk = blockIdx.y;
  const int b = bh >> 3, h = bh & 7;
  const int t0 = S_LEN - 512 + chunk * 32;
  const int tid = threadIdx.x;
  const int d = tid >> 1;
  const int eh = (tid & 1) * 64;

  __shared__ float ks[32][128];
  __shared__ float vsm[32][128];
  __shared__ float bs[32];

  const size_t bh_off = ((size_t)b * S_LEN) * INNER_DIM + (size_t)h * 128;
  for (int u = tid; u < 32 * 16; u += 256) {
    int r = u >> 4, c8 = (u & 15) * 8;
    bf16x8 kv = *(const bf16x8*)&k[bh_off + (size_t)(t0 + r) * INNER_DIM + c8];
    bf16x8 vv = *(const bf16x8*)&v[bh_off + (size_t)(t0 + r) * INNER_DIM + c8];
#pragma unroll
    for (int j = 0; j < 8; j++) {
      ks[r][c8 + j] = (float)kv[j];
      vsm[r][c8 + j] = (float)vv[j];
    }
  }
  if (tid < 32) bs[tid] = beta[((size_t)b * S_LEN + t0 + tid) * 8 + h];
  __syncthreads();

  const float lad = la_d[h * 128 + d];
  float acc[64];
#pragma unroll
  for (int e = 0; e < 64; e++) acc[e] = 0.0f;

  for (int tl = 0; tl < 32; tl++) {
    int m = (S_LEN - 1) - (t0 + tl);
    float f = __expf((float)m * lad);
    float coef = bs[tl] * ks[tl][d] * f;
    if (coef != 0.0f) {
#pragma unroll
      for (int e = 0; e < 64; e += 4) {
        float4 vv = *(const float4*)&vsm[tl][eh + e];
        acc[e + 0] = fmaf(coef, vv.x, acc[e + 0]);
        acc[e + 1] = fmaf(coef, vv.y, acc[e + 1]);
        acc[e + 2] = fmaf(coef, vv.z, acc[e + 2]);
        acc[e + 3] = fmaf(coef, vv.w, acc[e + 3]);
      }
    }
  }
  float* pp = part + (((size_t)chunk * 16 + bh) * 16384 + (size_t)d * 128 + eh);
#pragma unroll
  for (int e = 0; e < 64; e += 4) {
    float4 o = {acc[e + 0], acc[e + 1], acc[e + 2], acc[e + 3]};
    *(float4*)&pp[e] = o;
  }
}

// ---------------------------------------------------------------------------
// Stage 2: sum the 16 chunk partials into the final state.
// ---------------------------------------------------------------------------
__global__ __launch_bounds__(256) void state_reduce_kernel(
    const float* __restrict__ part, float* __restrict__ state) {
  size_t off = ((size_t)blockIdx.x * 256 + threadIdx.x) * 4;
  float4 s = {0.f, 0.f, 0.f, 0.f};
#pragma unroll
  for (int c = 0; c < 16; c++) {
    float4 p = *(const float4*)&part[(size_t)c * 262144 + off];
    s.x += p.x; s.y += p.y; s.z += p.z; s.w += p.w;
  }
  *(float4*)&state[off] = s;
}

// ---------------------------------------------------------------------------
extern "C" void kernel_launch(void* const* d_in, const int* in_sizes, int n_in,
                              void* d_out, int out_size, void* d_ws,
                              size_t ws_size, hipStream_t stream) {
  const float* x = (const float*)d_in[0];
  const float* Wq = (const float*)d_in[1];
  const float* Wk = (const float*)d_in[2];
  const float* Wv = (const float*)d_in[3];
  const float* Wo = (const float*)d_in[4];
  const float* Wb = (const float*)d_in[5];
  const float* bb = (const float*)d_in[6];
  const float* alog = (const float*)d_in[7];
  float* out = (float*)d_out;

  char* ws = (char*)d_ws;
  bf16* xb = (bf16*)(ws);                      // 16 MB (8M elems)
  float* part = (float*)(ws);                  // reuses xb after QKV GEMM
  bf16* wqkvb = (bf16*)(ws + 16777216UL);      // 12 MB (3 x 2,097,152 elems)
  bf16* wob = (bf16*)(ws + 29360128UL);        // 4 MB
  bf16* q = (bf16*)(ws + 33554432UL);          // 8 MB (4,194,304 elems)
  bf16* kk = (bf16*)(ws + 41943040UL);         // 8 MB
  bf16* vv = (bf16*)(ws + 50331648UL);         // 8 MB
  bf16* attnb = (bf16*)(ws + 58720256UL);      // 8 MB
  float* beta = (float*)(ws + 67108864UL);     // 128 KB
  float* la_mean = (float*)(ws + 67239936UL);  // 32 B
  float* la_d = (float*)(ws + 67239968UL);     // 4 KB

  convert_w_kernel<<<8192, 256, 0, stream>>>(Wq, Wk, Wv, Wo, wqkvb, wob);
  alpha_kernel<<<8, 64, 0, stream>>>(alog, la_mean, la_d);
  beta_xb_kernel<<<BATCH * S_LEN, 64, 0, stream>>>(x, Wb, bb, beta, xb);
  // fused QKV GEMM -> bf16 q/kk/vv (contiguous, strideC = 4,194,304 elems)
  gemm_bt_kernel<<<dim3(INNER_DIM / 128, (BATCH * S_LEN) / 128, 3), 256, 0,
                   stream>>>(xb, wqkvb, q, DMODEL, INNER_DIM, 2097152UL,
                             4194304UL, 1);
  rope_kernel<<<2048, 256, 0, stream>>>(q, kk);
  attn_kernel<<<dim3(S_LEN / 64, NHEADS, BATCH), 256, 0, stream>>>(
      q, kk, vv, beta, la_mean, attnb);
  state_partial_kernel<<<dim3(16, 16), 256, 0, stream>>>(kk, vv, beta, la_d,
                                                         part);
  state_reduce_kernel<<<256, 256, 0, stream>>>(part, out + 8388608);
  gemm_bt_kernel<<<dim3(DMODEL / 128, (BATCH * S_LEN) / 128, 1), 256, 0,
                   stream>>>(attnb, wob, out, INNER_DIM, DMODEL, 0, 0, 0);
}